// Round 2
// baseline (336.930 us; speedup 1.0000x reference)
//
#include <hip/hip_runtime.h>
#include <hip/hip_bf16.h>

#define D_MODEL 512
#define BATCH 4
#define SEQ 2048
#define ROWS (BATCH*SEQ)   // 8192

typedef unsigned short u16;
typedef short bf16x8 __attribute__((ext_vector_type(8)));
typedef float f32x4 __attribute__((ext_vector_type(4)));

__device__ __forceinline__ float bf2f(u16 u) {
    union { unsigned int i; float f; } v;
    v.i = ((unsigned int)u) << 16;
    return v.f;
}
__device__ __forceinline__ u16 f2bf(float f) {
    union { float f; unsigned int i; } v;
    v.f = f;
    unsigned int x = v.i;
    unsigned int r = (x >> 16) & 1u;
    x += 0x7fffu + r;           // round-to-nearest-even
    return (u16)(x >> 16);
}

// ---------------- split fp32 -> (hi, lo) bf16 ----------------
__global__ __launch_bounds__(256)
void split_f32_kernel(const float* __restrict__ in, u16* __restrict__ h,
                      u16* __restrict__ l, int n) {
    int i = (blockIdx.x * 256 + threadIdx.x) * 4;
    if (i >= n) return;
    float4 v = *(const float4*)(in + i);
    u16 hh[4], ll[4];
    float vv[4] = { v.x, v.y, v.z, v.w };
    #pragma unroll
    for (int j = 0; j < 4; ++j) {
        u16 hi = f2bf(vv[j]);
        hh[j] = hi;
        ll[j] = f2bf(vv[j] - bf2f(hi));
    }
    *(ushort4*)(h + i) = make_ushort4(hh[0], hh[1], hh[2], hh[3]);
    *(ushort4*)(l + i) = make_ushort4(ll[0], ll[1], ll[2], ll[3]);
}

// ---------------- GEMM: C[m,n] = scale * sum_k A[m,k]*B[n,k] + bias[n] ----------------
// m97-structure: global_load_lds width-16 staging into LINEAR LDS tiles,
// 128x128 block tile, BK=32, 4 waves (2x2), 4x4 acc frags per wave.
// A, B as (hi, lo) bf16 pairs; fp32 accumulate via 3 MFMAs (hh, hl, lh).
__global__ __launch_bounds__(256)
void gemm_bt(const u16* __restrict__ Ah, const u16* __restrict__ Al,
             const u16* __restrict__ Bh, const u16* __restrict__ Bl,
             const float* __restrict__ bias,
             float* __restrict__ outF, u16* __restrict__ outH, u16* __restrict__ outL,
             int K, int lda, int ldb, int ldc,
             long aStride, long bStride, long cStride,
             float scale, int transposeOut)
{
    // 4 tiles of [128][32] bf16, linear (global_load_lds needs contiguous dest)
    __shared__ u16 lds[4 * 128 * 32];   // 32 KiB
    const int tid  = threadIdx.x;
    const int lane = tid & 63;
    const int wave = tid >> 6;
    const int wr = wave >> 1, wc = wave & 1;
    const int bx = blockIdx.x, by = blockIdx.y, bz = blockIdx.z;

    const long aBase = (long)bz * aStride + (long)(bx * 128) * lda;
    const long bBase = (long)bz * bStride + (long)(by * 128) * ldb;

    // staging assignment: wave w owns tile w (0=Ah,1=Al,2=Bh,3=Bl)
    const u16* mySrc = (wave == 0) ? (Ah + aBase)
                     : (wave == 1) ? (Al + aBase)
                     : (wave == 2) ? (Bh + bBase)
                                   : (Bl + bBase);
    const int myLd = (wave < 2) ? lda : ldb;
    u16* myLds = &lds[wave * 4096];          // 8 KiB tile
    const int srow = lane >> 2;              // 0..15 row within 16-row chunk
    const int scol = (lane & 3) * 8;         // element col (16 B per lane)

    f32x4 acc[4][4] = {};

    const int frow = lane & 15;
    const int kofs = (lane >> 4) * 8;        // k element offset for b128 read

    for (int k0 = 0; k0 < K; k0 += 32) {
        __syncthreads();
        {
            const u16* sp = mySrc + k0 + (long)srow * myLd + scol;
            #pragma unroll
            for (int c = 0; c < 8; ++c) {
                __builtin_amdgcn_global_load_lds(
                    (const __attribute__((address_space(1))) unsigned int*)(sp + (long)(c * 16) * myLd),
                    (__attribute__((address_space(3))) unsigned int*)(myLds + c * 512),
                    16, 0, 0);
            }
        }
        __syncthreads();   // compiler drains vmcnt before barrier

        bf16x8 aH[4], aL[4], bH[4], bL[4];
        #pragma unroll
        for (int m = 0; m < 4; ++m) {
            int rA = wr*64 + m*16 + frow;
            aH[m] = *(const bf16x8*)&lds[0*4096 + rA*32 + kofs];
            aL[m] = *(const bf16x8*)&lds[1*4096 + rA*32 + kofs];
            int rB = wc*64 + m*16 + frow;
            bH[m] = *(const bf16x8*)&lds[2*4096 + rB*32 + kofs];
            bL[m] = *(const bf16x8*)&lds[3*4096 + rB*32 + kofs];
        }
        #pragma unroll
        for (int m = 0; m < 4; ++m)
            #pragma unroll
            for (int n = 0; n < 4; ++n) {
                acc[m][n] = __builtin_amdgcn_mfma_f32_16x16x32_bf16(aH[m], bH[n], acc[m][n], 0, 0, 0);
                acc[m][n] = __builtin_amdgcn_mfma_f32_16x16x32_bf16(aH[m], bL[n], acc[m][n], 0, 0, 0);
                acc[m][n] = __builtin_amdgcn_mfma_f32_16x16x32_bf16(aL[m], bH[n], acc[m][n], 0, 0, 0);
            }
    }

    // epilogue: C/D layout col=lane&15, row=(lane>>4)*4+reg  [m89-verified]
    const int rr = (lane >> 4) * 4;
    #pragma unroll
    for (int n = 0; n < 4; ++n) {
        int colL = by*128 + wc*64 + n*16 + frow;
        float bv_ = bias ? bias[colL] : 0.0f;
        #pragma unroll
        for (int m = 0; m < 4; ++m) {
            #pragma unroll
            for (int j = 0; j < 4; ++j) {
                int rowL = bx*128 + wr*64 + m*16 + rr + j;
                float val = acc[m][n][j] * scale + bv_;
                if (outF) {
                    outF[(long)bz*cStride + (long)rowL*ldc + colL] = val;
                } else if (transposeOut) {
                    // v path: [B][512][2048]; rowL is global (b*2048 + m)
                    int b = rowL >> 11;
                    int mrow = rowL & 2047;
                    long idx = (long)b*1048576 + (long)colL*2048 + mrow;
                    u16 h = f2bf(val);
                    outH[idx] = h;
                    outL[idx] = f2bf(val - bf2f(h));
                } else {
                    long idx = (long)bz*cStride + (long)rowL*ldc + colL;
                    u16 h = f2bf(val);
                    outH[idx] = h;
                    outL[idx] = f2bf(val - bf2f(h));
                }
            }
        }
    }
}

// ---------------- row softmax over 2048, in-place on (hi, lo) pair ----------------
__global__ __launch_bounds__(256)
void softmax_kernel(u16* __restrict__ sh, u16* __restrict__ sl)
{
    const long base = (long)blockIdx.x * 2048;
    const int tid = threadIdx.x;
    const int lane = tid & 63, wave = tid >> 6;
    u16* hp = sh + base + tid * 8;
    u16* lp = sl + base + tid * 8;
    bf16x8 hv = *(const bf16x8*)hp;
    bf16x8 lv = *(const bf16x8*)lp;
    float s[8];
    #pragma unroll
    for (int j = 0; j < 8; ++j) s[j] = bf2f((u16)hv[j]) + bf2f((u16)lv[j]);

    float mx = s[0];
    #pragma unroll
    for (int j = 1; j < 8; ++j) mx = fmaxf(mx, s[j]);
    #pragma unroll
    for (int off = 32; off >= 1; off >>= 1) mx = fmaxf(mx, __shfl_xor(mx, off));
    __shared__ float red[8];
    if (lane == 0) red[wave] = mx;
    __syncthreads();
    mx = fmaxf(fmaxf(red[0], red[1]), fmaxf(red[2], red[3]));

    float e[8], sum = 0.f;
    #pragma unroll
    for (int j = 0; j < 8; ++j) { e[j] = __expf(s[j] - mx); sum += e[j]; }
    #pragma unroll
    for (int off = 32; off >= 1; off >>= 1) sum += __shfl_xor(sum, off);
    if (lane == 0) red[4 + wave] = sum;
    __syncthreads();
    sum = red[4] + red[5] + red[6] + red[7];
    float inv = 1.0f / sum;

    bf16x8 ho, lo_;
    #pragma unroll
    for (int j = 0; j < 8; ++j) {
        float pv = e[j] * inv;
        u16 h = f2bf(pv);
        ho[j] = (short)h;
        lo_[j] = (short)f2bf(pv - bf2f(h));
    }
    *(bf16x8*)hp = ho;
    *(bf16x8*)lp = lo_;
}

extern "C" void kernel_launch(void* const* d_in, const int* in_sizes, int n_in,
                              void* d_out, int out_size, void* d_ws, size_t ws_size,
                              hipStream_t stream)
{
    const float* x  = (const float*)d_in[0];
    const float* Wq = (const float*)d_in[1];
    const float* bq = (const float*)d_in[2];
    const float* Wk = (const float*)d_in[3];
    const float* bk = (const float*)d_in[4];
    const float* Wv = (const float*)d_in[5];
    const float* bv = (const float*)d_in[6];
    const float* Wo = (const float*)d_in[7];
    const float* bo = (const float*)d_in[8];

    char* p = (char*)d_ws;
    auto alloc = [&](size_t bytes) { char* r = p; p += (bytes + 255) & ~(size_t)255; return r; };

    const size_t XE = (size_t)ROWS * D_MODEL;     // 4,194,304
    const size_t WE = (size_t)D_MODEL * D_MODEL;  // 262,144
    const size_t SE = (size_t)BATCH * SEQ * SEQ;  // 16,777,216

    u16* xh  = (u16*)alloc(XE * 2);
    u16* xl  = (u16*)alloc(XE * 2);
    u16* wqh = (u16*)alloc(WE * 2);
    u16* wql = (u16*)alloc(WE * 2);
    u16* wkh = (u16*)alloc(WE * 2);
    u16* wkl = (u16*)alloc(WE * 2);
    u16* wvh = (u16*)alloc(WE * 2);
    u16* wvl = (u16*)alloc(WE * 2);
    u16* woh = (u16*)alloc(WE * 2);
    u16* wol = (u16*)alloc(WE * 2);
    u16* qh  = (u16*)alloc(XE * 2);
    u16* ql  = (u16*)alloc(XE * 2);
    u16* kh  = (u16*)alloc(XE * 2);
    u16* kl  = (u16*)alloc(XE * 2);
    u16* vTh = (u16*)alloc(XE * 2);
    u16* vTl = (u16*)alloc(XE * 2);
    u16* sh  = (u16*)alloc(SE * 2);
    u16* sl  = (u16*)alloc(SE * 2);
    // att (split) aliases x's split buffers — x is dead after the V projection
    u16* ath = xh;
    u16* atl = xl;

    // 1. splits
    split_f32_kernel<<<XE / 1024, 256, 0, stream>>>(x,  xh,  xl,  (int)XE);
    split_f32_kernel<<<WE / 1024, 256, 0, stream>>>(Wq, wqh, wql, (int)WE);
    split_f32_kernel<<<WE / 1024, 256, 0, stream>>>(Wk, wkh, wkl, (int)WE);
    split_f32_kernel<<<WE / 1024, 256, 0, stream>>>(Wv, wvh, wvl, (int)WE);
    split_f32_kernel<<<WE / 1024, 256, 0, stream>>>(Wo, woh, wol, (int)WE);

    // 2. q = x@Wq^T + bq ; k = x@Wk^T + bk ; v = x@Wv^T + bv (transposed store)
    gemm_bt<<<dim3(64, 4, 1), 256, 0, stream>>>(xh, xl, wqh, wql, bq,
        nullptr, qh, ql, 512, 512, 512, 512, 0, 0, 0, 1.0f, 0);
    gemm_bt<<<dim3(64, 4, 1), 256, 0, stream>>>(xh, xl, wkh, wkl, bk,
        nullptr, kh, kl, 512, 512, 512, 512, 0, 0, 0, 1.0f, 0);
    gemm_bt<<<dim3(64, 4, 1), 256, 0, stream>>>(xh, xl, wvh, wvl, bv,
        nullptr, vTh, vTl, 512, 512, 512, 512, 0, 0, 0, 1.0f, 1);

    // 3. scores = q@k^T * 1/sqrt(512)   [per batch]
    gemm_bt<<<dim3(16, 16, 4), 256, 0, stream>>>(qh, ql, kh, kl, nullptr,
        nullptr, sh, sl, 512, 512, 512, 2048,
        (long)SEQ * 512, (long)SEQ * 512, (long)SEQ * SEQ,
        0.044194173824159216f, 0);

    // 4. softmax rows (in-place on hi/lo pair)
    softmax_kernel<<<ROWS, 256, 0, stream>>>(sh, sl);

    // 5. att = p @ v   [per batch; B operand = vT]
    gemm_bt<<<dim3(16, 4, 4), 256, 0, stream>>>(sh, sl, vTh, vTl, nullptr,
        nullptr, ath, atl, 2048, 2048, 2048, 512,
        (long)SEQ * SEQ, (long)512 * SEQ, (long)SEQ * 512,
        1.0f, 0);

    // 6. out = att @ Wo^T + bo  (fp32 to d_out)
    gemm_bt<<<dim3(64, 4, 1), 256, 0, stream>>>(ath, atl, woh, wol, bo,
        (float*)d_out, nullptr, nullptr, 512, 512, 512, 512,
        0, 0, 0, 1.0f, 0);
}

// Round 4
// 275.207 us; speedup vs baseline: 1.2243x; 1.2243x over previous
//
#include <hip/hip_runtime.h>
#include <hip/hip_bf16.h>

#define D_MODEL 512
#define BATCH 4
#define SEQ 2048
#define ROWS (BATCH*SEQ)   // 8192

typedef unsigned short u16;
typedef short bf16x8 __attribute__((ext_vector_type(8)));
typedef float f32x4 __attribute__((ext_vector_type(4)));

__device__ __forceinline__ float bf2f(u16 u) {
    union { unsigned int i; float f; } v;
    v.i = ((unsigned int)u) << 16;
    return v.f;
}
__device__ __forceinline__ u16 f2bf(float f) {
    union { float f; unsigned int i; } v;
    v.f = f;
    unsigned int x = v.i;
    unsigned int r = (x >> 16) & 1u;
    x += 0x7fffu + r;           // round-to-nearest-even
    return (u16)(x >> 16);
}

// ---------------- split fp32 -> (hi, lo) bf16 ----------------
__global__ __launch_bounds__(256)
void split_f32_kernel(const float* __restrict__ in, u16* __restrict__ h,
                      u16* __restrict__ l, int n) {
    int i = (blockIdx.x * 256 + threadIdx.x) * 4;
    if (i >= n) return;
    float4 v = *(const float4*)(in + i);
    u16 hh[4], ll[4];
    float vv[4] = { v.x, v.y, v.z, v.w };
    #pragma unroll
    for (int j = 0; j < 4; ++j) {
        u16 hi = f2bf(vv[j]);
        hh[j] = hi;
        ll[j] = f2bf(vv[j] - bf2f(hi));
    }
    *(ushort4*)(h + i) = make_ushort4(hh[0], hh[1], hh[2], hh[3]);
    *(ushort4*)(l + i) = make_ushort4(ll[0], ll[1], ll[2], ll[3]);
}

// ---------------- GEMM: C[m,n] = scale * sum_k A[m,k]*B[n,k] + bias[n] ----------------
// T3-minimum pipeline: double-buffered LDS, prefetch(t+1) issued BEFORE
// compute(t), single __syncthreads per K-step (its vmcnt(0) drain lands AFTER
// compute, so next-tile loads fly under the MFMAs).
// BM=128, BK=32, 4 waves (2x2); NF = n-frags per wave => BN = 32*NF.
// A, B as (hi, lo) bf16 pairs; fp32 accumulate via 3 MFMAs (hh, hl, lh).
template<int NF>
__global__ __launch_bounds__(256)
void gemm_bt(const u16* __restrict__ Ah, const u16* __restrict__ Al,
             const u16* __restrict__ Bh, const u16* __restrict__ Bl,
             const float* __restrict__ bias,
             float* __restrict__ outF, u16* __restrict__ outH, u16* __restrict__ outL,
             int K, int lda, int ldb, int ldc,
             long aStride, long bStride, long cStride,
             float scale, int transposeOut)
{
    constexpr int BN     = 32 * NF;
    constexpr int TILE_A = 128 * 32;          // u16 elems per A tile
    constexpr int TILE_B = BN * 32;
    constexpr int BUFSZ  = 2 * TILE_A + 2 * TILE_B;
    constexpr int BCH    = BN / 16;           // 1KiB chunks per B tile
    __shared__ u16 lds[2 * BUFSZ];

    const int tid  = threadIdx.x;
    const int lane = tid & 63;
    const int wave = tid >> 6;
    const int wr = wave >> 1, wc = wave & 1;
    const int bx = blockIdx.x, by = blockIdx.y, bz = blockIdx.z;

    const long aBase = (long)bz * aStride + (long)(bx * 128) * lda;
    const long bBase = (long)bz * bStride + (long)(by * BN) * ldb;

    // staging: wave w owns tile w (0=Ah,1=Al,2=Bh,3=Bl)
    const u16* mySrc = (wave == 0) ? (Ah + aBase)
                     : (wave == 1) ? (Al + aBase)
                     : (wave == 2) ? (Bh + bBase)
                                   : (Bl + bBase);
    const int myLd  = (wave < 2) ? lda : ldb;
    const int myCh  = (wave < 2) ? 8 : BCH;
    const int myOfs = (wave == 0) ? 0 : (wave == 1) ? TILE_A
                    : (wave == 2) ? 2*TILE_A : (2*TILE_A + TILE_B);
    const long laneOfs = (long)(lane >> 2) * myLd + (lane & 3) * 8;

    auto stage = [&](int buf, int k0) {
        const u16* sp = mySrc + k0 + laneOfs;
        u16* dst = &lds[buf * BUFSZ + myOfs];
        #pragma unroll
        for (int c = 0; c < 8; ++c) {
            if (c < myCh) {
                __builtin_amdgcn_global_load_lds(
                    (const __attribute__((address_space(1))) unsigned int*)(sp + (long)(c * 16) * myLd),
                    (__attribute__((address_space(3))) unsigned int*)(dst + c * 512),
                    16, 0, 0);
            }
        }
    };

    f32x4 acc[4][NF] = {};

    const int frow = lane & 15;
    const int kofs = (lane >> 4) * 8;         // k element offset for b128 read

    const int nt = K >> 5;
    stage(0, 0);
    __syncthreads();                          // buf0 ready

    int cur = 0;
    for (int t = 0; t < nt; ++t) {
        if (t + 1 < nt) stage(cur ^ 1, (t + 1) << 5);   // async prefetch

        const int bb = cur * BUFSZ;
        bf16x8 aH[4], aL[4], bH[NF], bL[NF];
        #pragma unroll
        for (int m = 0; m < 4; ++m) {
            int rA = wr*64 + m*16 + frow;
            aH[m] = *(const bf16x8*)&lds[bb + rA*32 + kofs];
            aL[m] = *(const bf16x8*)&lds[bb + TILE_A + rA*32 + kofs];
        }
        #pragma unroll
        for (int n = 0; n < NF; ++n) {
            int rB = wc*(NF*16) + n*16 + frow;
            bH[n] = *(const bf16x8*)&lds[bb + 2*TILE_A + rB*32 + kofs];
            bL[n] = *(const bf16x8*)&lds[bb + 2*TILE_A + TILE_B + rB*32 + kofs];
        }
        #pragma unroll
        for (int m = 0; m < 4; ++m)
            #pragma unroll
            for (int n = 0; n < NF; ++n) {
                acc[m][n] = __builtin_amdgcn_mfma_f32_16x16x32_bf16(aH[m], bH[n], acc[m][n], 0, 0, 0);
                acc[m][n] = __builtin_amdgcn_mfma_f32_16x16x32_bf16(aH[m], bL[n], acc[m][n], 0, 0, 0);
                acc[m][n] = __builtin_amdgcn_mfma_f32_16x16x32_bf16(aL[m], bH[n], acc[m][n], 0, 0, 0);
            }

        __syncthreads();   // vmcnt(0)+lgkmcnt(0)+barrier: next buf ready, cur reusable
        cur ^= 1;
    }

    // epilogue: C/D layout col=lane&15, row=(lane>>4)*4+reg  [m89-verified]
    const int rr = (lane >> 4) * 4;
    #pragma unroll
    for (int n = 0; n < NF; ++n) {
        int colL = by*BN + wc*(NF*16) + n*16 + frow;
        float bv_ = bias ? bias[colL] : 0.0f;
        #pragma unroll
        for (int m = 0; m < 4; ++m) {
            #pragma unroll
            for (int j = 0; j < 4; ++j) {
                int rowL = bx*128 + wr*64 + m*16 + rr + j;
                float val = acc[m][n][j] * scale + bv_;
                if (outF) {
                    outF[(long)bz*cStride + (long)rowL*ldc + colL] = val;
                } else if (transposeOut) {
                    // v path: [B][512][2048]; rowL is global (b*2048 + m)
                    int b = rowL >> 11;
                    int mrow = rowL & 2047;
                    long idx = (long)b*1048576 + (long)colL*2048 + mrow;
                    u16 h = f2bf(val);
                    outH[idx] = h;
                    outL[idx] = f2bf(val - bf2f(h));
                } else {
                    long idx = (long)bz*cStride + (long)rowL*ldc + colL;
                    u16 h = f2bf(val);
                    outH[idx] = h;
                    outL[idx] = f2bf(val - bf2f(h));
                }
            }
        }
    }
}

// ---------------- row softmax over 2048, in-place on (hi, lo) pair ----------------
__global__ __launch_bounds__(256)
void softmax_kernel(u16* __restrict__ sh, u16* __restrict__ sl)
{
    const long base = (long)blockIdx.x * 2048;
    const int tid = threadIdx.x;
    const int lane = tid & 63, wave = tid >> 6;
    u16* hp = sh + base + tid * 8;
    u16* lp = sl + base + tid * 8;
    bf16x8 hv = *(const bf16x8*)hp;
    bf16x8 lv = *(const bf16x8*)lp;
    float s[8];
    #pragma unroll
    for (int j = 0; j < 8; ++j) s[j] = bf2f((u16)hv[j]) + bf2f((u16)lv[j]);

    float mx = s[0];
    #pragma unroll
    for (int j = 1; j < 8; ++j) mx = fmaxf(mx, s[j]);
    #pragma unroll
    for (int off = 32; off >= 1; off >>= 1) mx = fmaxf(mx, __shfl_xor(mx, off));
    __shared__ float red[8];
    if (lane == 0) red[wave] = mx;
    __syncthreads();
    mx = fmaxf(fmaxf(red[0], red[1]), fmaxf(red[2], red[3]));

    float e[8], sum = 0.f;
    #pragma unroll
    for (int j = 0; j < 8; ++j) { e[j] = __expf(s[j] - mx); sum += e[j]; }
    #pragma unroll
    for (int off = 32; off >= 1; off >>= 1) sum += __shfl_xor(sum, off);
    if (lane == 0) red[4 + wave] = sum;
    __syncthreads();
    sum = red[4] + red[5] + red[6] + red[7];
    float inv = 1.0f / sum;

    bf16x8 ho, lo_;
    #pragma unroll
    for (int j = 0; j < 8; ++j) {
        float pv = e[j] * inv;
        u16 h = f2bf(pv);
        ho[j] = (short)h;
        lo_[j] = (short)f2bf(pv - bf2f(h));
    }
    *(bf16x8*)hp = ho;
    *(bf16x8*)lp = lo_;
}

extern "C" void kernel_launch(void* const* d_in, const int* in_sizes, int n_in,
                              void* d_out, int out_size, void* d_ws, size_t ws_size,
                              hipStream_t stream)
{
    const float* x  = (const float*)d_in[0];
    const float* Wq = (const float*)d_in[1];
    const float* bq = (const float*)d_in[2];
    const float* Wk = (const float*)d_in[3];
    const float* bk = (const float*)d_in[4];
    const float* Wv = (const float*)d_in[5];
    const float* bv = (const float*)d_in[6];
    const float* Wo = (const float*)d_in[7];
    const float* bo = (const float*)d_in[8];

    char* p = (char*)d_ws;
    auto alloc = [&](size_t bytes) { char* r = p; p += (bytes + 255) & ~(size_t)255; return r; };

    const size_t XE = (size_t)ROWS * D_MODEL;     // 4,194,304
    const size_t WE = (size_t)D_MODEL * D_MODEL;  // 262,144
    const size_t SE = (size_t)BATCH * SEQ * SEQ;  // 16,777,216

    u16* xh  = (u16*)alloc(XE * 2);
    u16* xl  = (u16*)alloc(XE * 2);
    u16* wqh = (u16*)alloc(WE * 2);
    u16* wql = (u16*)alloc(WE * 2);
    u16* wkh = (u16*)alloc(WE * 2);
    u16* wkl = (u16*)alloc(WE * 2);
    u16* wvh = (u16*)alloc(WE * 2);
    u16* wvl = (u16*)alloc(WE * 2);
    u16* woh = (u16*)alloc(WE * 2);
    u16* wol = (u16*)alloc(WE * 2);
    u16* qh  = (u16*)alloc(XE * 2);
    u16* ql  = (u16*)alloc(XE * 2);
    u16* kh  = (u16*)alloc(XE * 2);
    u16* kl  = (u16*)alloc(XE * 2);
    u16* vTh = (u16*)alloc(XE * 2);
    u16* vTl = (u16*)alloc(XE * 2);
    u16* sh  = (u16*)alloc(SE * 2);
    u16* sl  = (u16*)alloc(SE * 2);
    // att (split) aliases x's split buffers — x is dead after the V projection
    u16* ath = xh;
    u16* atl = xl;

    // 1. splits
    split_f32_kernel<<<XE / 1024, 256, 0, stream>>>(x,  xh,  xl,  (int)XE);
    split_f32_kernel<<<WE / 1024, 256, 0, stream>>>(Wq, wqh, wql, (int)WE);
    split_f32_kernel<<<WE / 1024, 256, 0, stream>>>(Wk, wkh, wkl, (int)WE);
    split_f32_kernel<<<WE / 1024, 256, 0, stream>>>(Wv, wvh, wvl, (int)WE);
    split_f32_kernel<<<WE / 1024, 256, 0, stream>>>(Wo, woh, wol, (int)WE);

    // 2. q/k/v projections (BN=64 tiles: 512 blocks, 3 blocks/CU by LDS)
    gemm_bt<2><<<dim3(64, 8, 1), 256, 0, stream>>>(xh, xl, wqh, wql, bq,
        nullptr, qh, ql, 512, 512, 512, 512, 0, 0, 0, 1.0f, 0);
    gemm_bt<2><<<dim3(64, 8, 1), 256, 0, stream>>>(xh, xl, wkh, wkl, bk,
        nullptr, kh, kl, 512, 512, 512, 512, 0, 0, 0, 1.0f, 0);
    gemm_bt<2><<<dim3(64, 8, 1), 256, 0, stream>>>(xh, xl, wvh, wvl, bv,
        nullptr, vTh, vTl, 512, 512, 512, 512, 0, 0, 0, 1.0f, 1);

    // 3. scores = q@k^T * 1/sqrt(512)   [per batch; BN=128: 1024 blocks]
    gemm_bt<4><<<dim3(16, 16, 4), 256, 0, stream>>>(qh, ql, kh, kl, nullptr,
        nullptr, sh, sl, 512, 512, 512, 2048,
        (long)SEQ * 512, (long)SEQ * 512, (long)SEQ * SEQ,
        0.044194173824159216f, 0);

    // 4. softmax rows (in-place on hi/lo pair)
    softmax_kernel<<<ROWS, 256, 0, stream>>>(sh, sl);

    // 5. att = p @ v   [per batch; B operand = vT; BN=64: 512 blocks]
    gemm_bt<2><<<dim3(16, 8, 4), 256, 0, stream>>>(sh, sl, vTh, vTl, nullptr,
        nullptr, ath, atl, 2048, 2048, 2048, 512,
        (long)SEQ * SEQ, (long)512 * SEQ, (long)SEQ * 512,
        1.0f, 0);

    // 6. out = att @ Wo^T + bo  (fp32 to d_out)
    gemm_bt<2><<<dim3(64, 8, 1), 256, 0, stream>>>(ath, atl, woh, wol, bo,
        (float*)d_out, nullptr, nullptr, 512, 512, 512, 512,
        0, 0, 0, 1.0f, 0);
}

// Round 5
// 191.598 us; speedup vs baseline: 1.7585x; 1.4364x over previous
//
#include <hip/hip_runtime.h>
#include <hip/hip_bf16.h>

#define D_MODEL 512
#define BATCH 4
#define SEQ 2048
#define ROWS (BATCH*SEQ)   // 8192

typedef unsigned short u16;
typedef short bf16x8 __attribute__((ext_vector_type(8)));
typedef float f32x4 __attribute__((ext_vector_type(4)));

__device__ __forceinline__ float bf2f(u16 u) {
    union { unsigned int i; float f; } v;
    v.i = ((unsigned int)u) << 16;
    return v.f;
}
__device__ __forceinline__ u16 f2bf(float f) {
    union { float f; unsigned int i; } v;
    v.f = f;
    unsigned int x = v.i;
    unsigned int r = (x >> 16) & 1u;
    x += 0x7fffu + r;           // round-to-nearest-even
    return (u16)(x >> 16);
}

// ---------------- split fp32 -> (hi, lo) bf16 ----------------
__global__ __launch_bounds__(256)
void split_f32_kernel(const float* __restrict__ in, u16* __restrict__ h,
                      u16* __restrict__ l, int n) {
    int i = (blockIdx.x * 256 + threadIdx.x) * 4;
    if (i >= n) return;
    float4 v = *(const float4*)(in + i);
    u16 hh[4], ll[4];
    float vv[4] = { v.x, v.y, v.z, v.w };
    #pragma unroll
    for (int j = 0; j < 4; ++j) {
        u16 hi = f2bf(vv[j]);
        hh[j] = hi;
        ll[j] = f2bf(vv[j] - bf2f(hi));
    }
    *(ushort4*)(h + i) = make_ushort4(hh[0], hh[1], hh[2], hh[3]);
    *(ushort4*)(l + i) = make_ushort4(ll[0], ll[1], ll[2], ll[3]);
}

// ---------------- GEMM: C[m,n] = scale * sum_k A[m,k]*B[n,k] + bias[n] ----------------
// T3-minimum pipeline: double-buffered LDS, prefetch(t+1) issued BEFORE
// compute(t), single __syncthreads per K-step.
// BM=128, BK=32, 4 waves (2x2); NF = n-frags per wave => BN = 32*NF.
// AT/BT = number of split parts (1 = bf16-only hi, 2 = hi+lo).
// MFMA terms: hh (+ hl if BT==2) (+ lh if AT==2); ll always dropped.
template<int NF, int AT, int BT>
__global__ __launch_bounds__(256)
void gemm_bt(const u16* __restrict__ Ah, const u16* __restrict__ Al,
             const u16* __restrict__ Bh, const u16* __restrict__ Bl,
             const float* __restrict__ bias,
             float* __restrict__ outF, u16* __restrict__ outH, u16* __restrict__ outL,
             int K, int lda, int ldb, int ldc,
             long aStride, long bStride, long cStride,
             float scale, int transposeOut)
{
    constexpr int BN     = 32 * NF;
    constexpr int TILE_A = 128 * 32;          // u16 elems per A tile
    constexpr int TILE_B = BN * 32;
    constexpr int ACH    = 8;                 // 1KiB chunks per A tile
    constexpr int BCH    = BN / 16;           // 1KiB chunks per B tile
    constexpr int NCH    = AT*ACH + BT*BCH;   // total chunks (16/12/24: all %4==0)
    constexpr int CPW    = NCH / 4;           // chunks per wave
    constexpr int BUFSZ  = AT*TILE_A + BT*TILE_B;
    __shared__ u16 lds[2 * BUFSZ];

    const int tid  = threadIdx.x;
    const int lane = tid & 63;
    const int wave = tid >> 6;
    const int wr = wave >> 1, wc = wave & 1;
    const int bx = blockIdx.x, by = blockIdx.y, bz = blockIdx.z;

    const long aBase = (long)bz * aStride + (long)(bx * 128) * lda;
    const long bBase = (long)bz * bStride + (long)(by * BN) * ldb;

    // Precompute this wave's staging chunks: chunk = 16 rows x 32 elems (1 KiB).
    // global_load_lds: per-lane global src, wave-uniform LDS dst (+lane*16B).
    const u16* csrc[CPW];
    unsigned cdst[CPW];
    #pragma unroll
    for (int i = 0; i < CPW; ++i) {
        int c = wave + i * 4;
        const u16* sb; int ld, lofs, row;
        if (c < AT * ACH) {
            int t = c >> 3;               // A part index
            row = (c & 7) * 16;
            sb = (t == 0 ? Ah : Al) + aBase;
            ld = lda; lofs = t * TILE_A;
        } else {
            int cb = c - AT * ACH;
            int t = cb / BCH;
            row = (cb % BCH) * 16;
            sb = (t == 0 ? Bh : Bl) + bBase;
            ld = ldb; lofs = AT * TILE_A + t * TILE_B;
        }
        csrc[i] = sb + (long)(row + (lane >> 2)) * ld + (lane & 3) * 8;
        cdst[i] = lofs + row * 32;
    }

    auto stage = [&](int buf, int k0) {
        #pragma unroll
        for (int i = 0; i < CPW; ++i) {
            __builtin_amdgcn_global_load_lds(
                (const __attribute__((address_space(1))) unsigned int*)(csrc[i] + k0),
                (__attribute__((address_space(3))) unsigned int*)(&lds[buf * BUFSZ + cdst[i]]),
                16, 0, 0);
        }
    };

    f32x4 acc[4][NF] = {};

    const int frow = lane & 15;
    const int kofs = (lane >> 4) * 8;         // k element offset for b128 read

    const int nt = K >> 5;
    stage(0, 0);
    __syncthreads();                          // buf0 ready

    int cur = 0;
    for (int t = 0; t < nt; ++t) {
        if (t + 1 < nt) stage(cur ^ 1, (t + 1) << 5);   // async prefetch

        const int bb = cur * BUFSZ;
        bf16x8 aH[4], aL[4], bH[NF], bL[NF];
        #pragma unroll
        for (int m = 0; m < 4; ++m) {
            int rA = wr*64 + m*16 + frow;
            aH[m] = *(const bf16x8*)&lds[bb + rA*32 + kofs];
            if constexpr (AT == 2)
                aL[m] = *(const bf16x8*)&lds[bb + TILE_A + rA*32 + kofs];
        }
        #pragma unroll
        for (int n = 0; n < NF; ++n) {
            int rB = wc*(NF*16) + n*16 + frow;
            bH[n] = *(const bf16x8*)&lds[bb + AT*TILE_A + rB*32 + kofs];
            if constexpr (BT == 2)
                bL[n] = *(const bf16x8*)&lds[bb + AT*TILE_A + TILE_B + rB*32 + kofs];
        }
        #pragma unroll
        for (int m = 0; m < 4; ++m)
            #pragma unroll
            for (int n = 0; n < NF; ++n) {
                acc[m][n] = __builtin_amdgcn_mfma_f32_16x16x32_bf16(aH[m], bH[n], acc[m][n], 0, 0, 0);
                if constexpr (BT == 2)
                    acc[m][n] = __builtin_amdgcn_mfma_f32_16x16x32_bf16(aH[m], bL[n], acc[m][n], 0, 0, 0);
                if constexpr (AT == 2)
                    acc[m][n] = __builtin_amdgcn_mfma_f32_16x16x32_bf16(aL[m], bH[n], acc[m][n], 0, 0, 0);
            }

        __syncthreads();   // vmcnt(0)+lgkmcnt(0)+barrier: next buf ready, cur reusable
        cur ^= 1;
    }

    // epilogue: C/D layout col=lane&15, row=(lane>>4)*4+reg  [m89-verified]
    const int rr = (lane >> 4) * 4;
    #pragma unroll
    for (int n = 0; n < NF; ++n) {
        int colL = by*BN + wc*(NF*16) + n*16 + frow;
        float bv_ = bias ? bias[colL] : 0.0f;
        #pragma unroll
        for (int m = 0; m < 4; ++m) {
            #pragma unroll
            for (int j = 0; j < 4; ++j) {
                int rowL = bx*128 + wr*64 + m*16 + rr + j;
                float val = acc[m][n][j] * scale + bv_;
                if (outF) {
                    outF[(long)bz*cStride + (long)rowL*ldc + colL] = val;
                } else if (transposeOut) {
                    // v path: [B][512][2048]; rowL is global (b*2048 + m)
                    int b = rowL >> 11;
                    int mrow = rowL & 2047;
                    long idx = (long)b*1048576 + (long)colL*2048 + mrow;
                    u16 h = f2bf(val);
                    outH[idx] = h;
                    if (outL) outL[idx] = f2bf(val - bf2f(h));
                } else {
                    long idx = (long)bz*cStride + (long)rowL*ldc + colL;
                    u16 h = f2bf(val);
                    outH[idx] = h;
                    if (outL) outL[idx] = f2bf(val - bf2f(h));
                }
            }
        }
    }
}

// ---------------- row softmax over 2048, in-place, bf16 ----------------
__global__ __launch_bounds__(256)
void softmax_kernel(u16* __restrict__ sh)
{
    const long base = (long)blockIdx.x * 2048;
    const int tid = threadIdx.x;
    const int lane = tid & 63, wave = tid >> 6;
    u16* hp = sh + base + tid * 8;
    bf16x8 hv = *(const bf16x8*)hp;
    float s[8];
    #pragma unroll
    for (int j = 0; j < 8; ++j) s[j] = bf2f((u16)hv[j]);

    float mx = s[0];
    #pragma unroll
    for (int j = 1; j < 8; ++j) mx = fmaxf(mx, s[j]);
    #pragma unroll
    for (int off = 32; off >= 1; off >>= 1) mx = fmaxf(mx, __shfl_xor(mx, off));
    __shared__ float red[8];
    if (lane == 0) red[wave] = mx;
    __syncthreads();
    mx = fmaxf(fmaxf(red[0], red[1]), fmaxf(red[2], red[3]));

    float e[8], sum = 0.f;
    #pragma unroll
    for (int j = 0; j < 8; ++j) { e[j] = __expf(s[j] - mx); sum += e[j]; }
    #pragma unroll
    for (int off = 32; off >= 1; off >>= 1) sum += __shfl_xor(sum, off);
    if (lane == 0) red[4 + wave] = sum;
    __syncthreads();
    sum = red[4] + red[5] + red[6] + red[7];
    float inv = 1.0f / sum;

    bf16x8 ho;
    #pragma unroll
    for (int j = 0; j < 8; ++j) ho[j] = (short)f2bf(e[j] * inv);
    *(bf16x8*)hp = ho;
}

extern "C" void kernel_launch(void* const* d_in, const int* in_sizes, int n_in,
                              void* d_out, int out_size, void* d_ws, size_t ws_size,
                              hipStream_t stream)
{
    const float* x  = (const float*)d_in[0];
    const float* Wq = (const float*)d_in[1];
    const float* bq = (const float*)d_in[2];
    const float* Wk = (const float*)d_in[3];
    const float* bk = (const float*)d_in[4];
    const float* Wv = (const float*)d_in[5];
    const float* bv = (const float*)d_in[6];
    const float* Wo = (const float*)d_in[7];
    const float* bo = (const float*)d_in[8];

    char* p = (char*)d_ws;
    auto alloc = [&](size_t bytes) { char* r = p; p += (bytes + 255) & ~(size_t)255; return r; };

    const size_t XE = (size_t)ROWS * D_MODEL;     // 4,194,304
    const size_t WE = (size_t)D_MODEL * D_MODEL;  // 262,144
    const size_t SE = (size_t)BATCH * SEQ * SEQ;  // 16,777,216

    u16* xh  = (u16*)alloc(XE * 2);
    u16* xl  = (u16*)alloc(XE * 2);
    u16* wqh = (u16*)alloc(WE * 2);
    u16* wql = (u16*)alloc(WE * 2);
    u16* wkh = (u16*)alloc(WE * 2);
    u16* wkl = (u16*)alloc(WE * 2);
    u16* wvh = (u16*)alloc(WE * 2);
    u16* wvl = (u16*)alloc(WE * 2);
    u16* woh = (u16*)alloc(WE * 2);
    u16* wol = (u16*)alloc(WE * 2);
    u16* qh  = (u16*)alloc(XE * 2);
    u16* kh  = (u16*)alloc(XE * 2);
    u16* vTh = (u16*)alloc(XE * 2);
    u16* sh  = (u16*)alloc(SE * 2);
    // att (split) aliases x's split buffers — x is dead after the V projection
    u16* ath = xh;
    u16* atl = xl;

    // 1. splits
    split_f32_kernel<<<XE / 1024, 256, 0, stream>>>(x,  xh,  xl,  (int)XE);
    split_f32_kernel<<<WE / 1024, 256, 0, stream>>>(Wq, wqh, wql, (int)WE);
    split_f32_kernel<<<WE / 1024, 256, 0, stream>>>(Wk, wkh, wkl, (int)WE);
    split_f32_kernel<<<WE / 1024, 256, 0, stream>>>(Wv, wvh, wvl, (int)WE);
    split_f32_kernel<<<WE / 1024, 256, 0, stream>>>(Wo, woh, wol, (int)WE);

    // 2. q/k/v projections: split x @ split W (3-term), bf16-only outputs
    gemm_bt<2,2,2><<<dim3(64, 8, 1), 256, 0, stream>>>(xh, xl, wqh, wql, bq,
        nullptr, qh, nullptr, 512, 512, 512, 512, 0, 0, 0, 1.0f, 0);
    gemm_bt<2,2,2><<<dim3(64, 8, 1), 256, 0, stream>>>(xh, xl, wkh, wkl, bk,
        nullptr, kh, nullptr, 512, 512, 512, 512, 0, 0, 0, 1.0f, 0);
    gemm_bt<2,2,2><<<dim3(64, 8, 1), 256, 0, stream>>>(xh, xl, wvh, wvl, bv,
        nullptr, vTh, nullptr, 512, 512, 512, 512, 0, 0, 0, 1.0f, 1);

    // 3. scores = q@k^T * 1/sqrt(512): pure bf16, 1-term
    gemm_bt<4,1,1><<<dim3(16, 16, 4), 256, 0, stream>>>(qh, nullptr, kh, nullptr, nullptr,
        nullptr, sh, nullptr, 512, 512, 512, 2048,
        (long)SEQ * 512, (long)SEQ * 512, (long)SEQ * SEQ,
        0.044194173824159216f, 0);

    // 4. softmax rows (bf16 in/out)
    softmax_kernel<<<ROWS, 256, 0, stream>>>(sh);

    // 5. att = p @ v: pure bf16, 1-term; split output (feeds final 3-term proj)
    gemm_bt<2,1,1><<<dim3(16, 8, 4), 256, 0, stream>>>(sh, nullptr, vTh, nullptr, nullptr,
        nullptr, ath, atl, 2048, 2048, 2048, 512,
        (long)SEQ * SEQ, (long)512 * SEQ, (long)SEQ * 512,
        1.0f, 0);

    // 6. out = att @ Wo^T + bo: split att @ split Wo (3-term), fp32 out
    gemm_bt<2,2,2><<<dim3(64, 8, 1), 256, 0, stream>>>(ath, atl, woh, wol, bo,
        (float*)d_out, nullptr, nullptr, 512, 512, 512, 512,
        0, 0, 0, 1.0f, 0);
}